// Round 1
// baseline (661.694 us; speedup 1.0000x reference)
//
#include <hip/hip_runtime.h>
#include <math.h>

// Problem constants (from reference setup_inputs)
#define NSRC 8          // N-1 source frames
#define CCH  32         // channels
#define HH   192
#define WW   256
#define SS   9
#define GG   8

// f strides in floats: (N, C, H, W, S) contiguous
#define F_SC (HH*WW*SS)        // 442368
#define F_SH (WW*SS)           // 2304
#define F_SN (CCH*HH*WW*SS)    // 14155776

// workspace layout (floats)
#define WS_M   0      // 32x32  M' = Wp^T Wp / sqrt(C)
#define WS_V   1024   // 32     v' = Wp^T bp / sqrt(C)
#define WS_BB  1056   // 1      bb' = |bp|^2 / sqrt(C)

#define TILE_W 32

// ---------------------------------------------------------------------------
// k0: tiny precompute of M', v', bb'   (unchanged, verified)
// ---------------------------------------------------------------------------
__global__ void k0_precompute(const float* __restrict__ Wp,
                              const float* __restrict__ bp,
                              float* __restrict__ ws) {
    const float inv_sqrtC = 0.17677669529663687f;  // 1/sqrt(32)
    int t = threadIdx.x;
    for (int idx = t; idx < 1024; idx += 256) {
        int c = idx >> 5, c2 = idx & 31;
        float acc = 0.f;
        for (int d = 0; d < 32; ++d) acc = fmaf(Wp[d*32 + c], Wp[d*32 + c2], acc);
        ws[WS_M + idx] = acc * inv_sqrtC;
    }
    if (t < 32) {
        float acc = 0.f;
        for (int d = 0; d < 32; ++d) acc = fmaf(Wp[d*32 + t], bp[d], acc);
        ws[WS_V + t] = acc * inv_sqrtC;
    }
    if (t == 0) {
        float acc = 0.f;
        for (int d = 0; d < 32; ++d) acc = fmaf(bp[d], bp[d], acc);
        ws[WS_BB] = acc * inv_sqrtC;
    }
}

// ---------------------------------------------------------------------------
// Fused kernel, v2: barrier-free streaming phase 2.
//   - src frames have ZERO cross-thread reuse -> no LDS staging, no barriers.
//     Each thread (wi = pixel, j = channel group) loads its own 4ch x 9s
//     (9 contiguous floats per channel; half-wave = 1152 B contiguous,
//     64B-line exact) directly to registers, double-set A/B pipelined.
//   - ref: only the s=4 plane is cross-thread reused -> 4 KB padded LDS.
//   - LDS ~19 KB (was 52 KB); phase-2 has no __syncthreads at all.
// Block = 256 threads = (wi 0..31 pixels) x (j 0..7 groups). Grid = (8, 192).
// ---------------------------------------------------------------------------

#define LOADF(ARR, frame) do {                                                \
    _Pragma("unroll")                                                         \
    for (int cc = 0; cc < 4; ++cc) {                                          \
        const float* p_ = fr + (long)(frame) * F_SN + (long)cc * F_SC;        \
        _Pragma("unroll")                                                     \
        for (int s = 0; s < SS; ++s) ARR[cc*SS + s] = p_[s];                  \
    }                                                                         \
} while (0)

#define CORR_STORE(ARR, n) do {                                               \
    float a0_ = 0.f, a1_ = 0.f, a2_ = 0.f, a3_ = 0.f;                         \
    _Pragma("unroll")                                                         \
    for (int s = 0; s < SS; ++s) {                                            \
        a0_ = fmaf(rref[0*SS + s], ARR[0*SS + s], a0_);                       \
        a1_ = fmaf(rref[1*SS + s], ARR[1*SS + s], a1_);                       \
        a2_ = fmaf(rref[2*SS + s], ARR[2*SS + s], a2_);                       \
        a3_ = fmaf(rref[3*SS + s], ARR[3*SS + s], a3_);                       \
    }                                                                         \
    out[(((long)(n) * GG + j) * HH + h) * WW + w0 + wi] = (a0_ + a1_) + (a2_ + a3_); \
} while (0)

__global__ __launch_bounds__(256) void k_fused(const float* __restrict__ f,
                                               const float* __restrict__ ws,
                                               float* __restrict__ out) {
    __shared__ float M_s[1024];        // 4 KB
    __shared__ float v_s[32];
    __shared__ float bb_s;
    __shared__ float s4[32 * 33];      // 4.2 KB: s=4 plane, pad 33 (conflict-free)
    __shared__ float lgp[32 * 73];     // 9.3 KB: padded partial logits
    __shared__ float att_s[32 * SS];

    const int t  = threadIdx.x;
    const int wi = t & 31;
    const int j  = t >> 5;             // 0..7 channel group
    const int w0 = blockIdx.x * TILE_W;
    const int h  = blockIdx.y;
    // frame-0 base for this thread's (channel-group, pixel), s=0
    const float* fr = f + (long)(4 * j) * F_SC + (long)h * F_SH + (long)(w0 + wi) * SS;

    // ---- stage constants ---------------------------------------------------
    ((float4*)M_s)[t] = ((const float4*)(ws + WS_M))[t];
    if (t < 32) v_s[t] = ws[WS_V + t];
    if (t == 0) bb_s = ws[WS_BB];

    // ---- ref: own 4 channels x 9 taps, direct global -> regs ---------------
    float rref[4 * SS];
    #pragma unroll
    for (int cc = 0; cc < 4; ++cc) {
        const float* p_ = fr + (long)cc * F_SC;
        #pragma unroll
        for (int s = 0; s < SS; ++s) rref[cc*SS + s] = p_[s];
    }

    // ---- prefetch src n=0 (frame 1) early; independent of phase 1 ----------
    float A[4 * SS], B[4 * SS];
    LOADF(A, 1);

    // ---- share the s=4 plane (the only cross-thread-reused ref data) -------
    #pragma unroll
    for (int cc = 0; cc < 4; ++cc)
        s4[wi * 33 + 4 * j + cc] = rref[cc * SS + 4];
    __syncthreads();          // S1: s4 + consts visible

    // ---- u = v' + M' * r4 (own 4 rows); partial logits ---------------------
    float u[4];
    #pragma unroll
    for (int cc = 0; cc < 4; ++cc) u[cc] = v_s[4 * j + cc];
    #pragma unroll
    for (int cp = 0; cp < 32; ++cp) {
        float r4 = s4[wi * 33 + cp];
        #pragma unroll
        for (int cc = 0; cc < 4; ++cc)
            u[cc] = fmaf(M_s[(4 * j + cc) * 32 + cp], r4, u[cc]);
    }

    float pb = 0.f;   // partial beta term
    #pragma unroll
    for (int cc = 0; cc < 4; ++cc) pb = fmaf(rref[cc * SS + 4], v_s[4 * j + cc], pb);

    float lgv[SS];
    #pragma unroll
    for (int s = 0; s < SS; ++s) lgv[s] = pb;
    #pragma unroll
    for (int cc = 0; cc < 4; ++cc) {
        float uc = u[cc];
        #pragma unroll
        for (int s = 0; s < SS; ++s) lgv[s] = fmaf(uc, rref[cc * SS + s], lgv[s]);
    }
    #pragma unroll
    for (int s = 0; s < SS; ++s) lgp[wi * 73 + j * SS + s] = lgv[s];
    __syncthreads();          // S2: partials visible

    // ---- softmax (32 leaders) ----------------------------------------------
    if (j == 0) {
        float lt[SS];
        #pragma unroll
        for (int s = 0; s < SS; ++s) lt[s] = bb_s;
        #pragma unroll
        for (int jj = 0; jj < 8; ++jj)
            #pragma unroll
            for (int s = 0; s < SS; ++s) lt[s] += lgp[wi * 73 + jj * SS + s];
        float m = lt[0];
        #pragma unroll
        for (int s = 1; s < SS; ++s) m = fmaxf(m, lt[s]);
        float e[SS], sum = 0.f;
        #pragma unroll
        for (int s = 0; s < SS; ++s) { e[s] = __expf(lt[s] - m); sum += e[s]; }
        float inv = 1.f / sum;
        #pragma unroll
        for (int s = 0; s < SS; ++s) att_s[wi * SS + s] = e[s] * inv;
    }
    __syncthreads();          // S3: att visible  (last barrier in the kernel)

    // ---- q = att * ref, built in place over rref ---------------------------
    {
        float a[SS];
        #pragma unroll
        for (int s = 0; s < SS; ++s) a[s] = att_s[wi * SS + s];
        #pragma unroll
        for (int cc = 0; cc < 4; ++cc)
            #pragma unroll
            for (int s = 0; s < SS; ++s)
                rref[cc * SS + s] *= a[s];
    }

    // ---- phase 2: barrier-free, software-pipelined A/B over 8 src frames ---
    // src n lives in f frame n+1. A holds n, B holds n+1; loads for the next
    // frame are issued before consuming the current one (counted waitcnts keep
    // them in flight; no __syncthreads -> no vmcnt(0) drain).
    #pragma unroll
    for (int n = 0; n < NSRC; n += 2) {
        LOADF(B, n + 2);                   // src n+1
        CORR_STORE(A, n);
        if (n + 2 < NSRC) LOADF(A, n + 3); // src n+2
        CORR_STORE(B, n + 1);
    }
}

// ---------------------------------------------------------------------------
extern "C" void kernel_launch(void* const* d_in, const int* in_sizes, int n_in,
                              void* d_out, int out_size, void* d_ws, size_t ws_size,
                              hipStream_t stream) {
    const float* f  = (const float*)d_in[0];
    const float* Wp = (const float*)d_in[1];
    const float* bp = (const float*)d_in[2];
    float* out = (float*)d_out;
    float* ws  = (float*)d_ws;

    k0_precompute<<<1, 256, 0, stream>>>(Wp, bp, ws);
    k_fused<<<dim3(WW / TILE_W, HH), 256, 0, stream>>>(f, ws, out);
}